// Round 12
// baseline (140.059 us; speedup 1.0000x reference)
//
#include <hip/hip_runtime.h>

// SpMM out = w[idx] * segment_sum(vals[:,None] * x[cols], rows, N)
//
// Ladder: R1 atomics 680 -> R5 CSR 232 -> R8 bucket-bin+reg-gather 150.5 ->
// R10 1-pass distribute 138.8 -> R11 LDS-sorted build 135.6.
// Harness fill/restore (~51us) is a fixed floor. Gather is LATENCY-bound
// (R6: warm replay 37GB/s; R9: col-phasing didn't move FETCH ~70-80MB floor).
//
// R12: maximize memory-level parallelism in gather:
//  - 2 blocks per 64-row bucket (1564 blocks x 256thr, half-bucket each);
//    LDS 11.4KB -> 8 blocks/CU -> 32 waves/CU (full occupancy, was ~24).
//  - unroll-8 row accumulation (8 x-row loads in flight per wave).
//  - build EPB 2048 -> 391 blocks (all CUs busy; R11's 196 left 60 idle).

#define FEAT_D 64
#define BROWS 64
#define BSH 6
#define MAXBKT 1024     // N <= 65536
#define LCAP 44         // per-row list cap; deg~Poisson(16), P(>44) ~ 1e-9
#define OVFCAP 16384
#define EPB 2048        // edges per build block
#define BBLOCK 512
#define EPT (EPB / BBLOCK)   // 4
#define GBLOCK 256      // gather: 4 waves; wave w owns 8 rows of its half

// ---------- build: LDS-staged counting sort, coalesced copy-out ----------
__global__ __launch_bounds__(BBLOCK) void build_kernel(
        const float* __restrict__ edge_vals,
        const int* __restrict__ edge_rows,
        const int* __restrict__ edge_cols,
        const int* __restrict__ idx_ptr,
        int* __restrict__ bktcnt,
        int2* __restrict__ pack,
        int* __restrict__ ovfcnt,
        int4* __restrict__ ovfbuf,
        int E, int NBKT, int cap) {
    __shared__ int2 stage[EPB];            // 16 KB bucket-ordered records
    __shared__ unsigned short sbkt[EPB];   // 4 KB bucket id per staged slot
    __shared__ int lh[MAXBKT];             // counts -> cursors
    __shared__ int lofs[MAXBKT];           // local exclusive offsets
    __shared__ int gbase[MAXBKT];          // reserved global run bases
    __shared__ int ssum[BBLOCK];
    const long long off = (long long)idx_ptr[0] * E;
    const int* rows = edge_rows + off;
    const int* cols = edge_cols + off;
    const float* vals = edge_vals + off;
    const int t = threadIdx.x;
    const int s = blockIdx.x * EPB;
    const int e2 = min(s + EPB, E);
    const int cnt_total = e2 - s;

    for (int k = t; k < NBKT; k += BBLOCK) lh[k] = 0;
    __syncthreads();

    // p1: count; cache record + bucket in registers
    int2 myrec[EPT];
    int mybkt[EPT];
#pragma unroll
    for (int k = 0; k < EPT; ++k) {
        const int g = s + t + k * BBLOCK;
        mybkt[k] = -1;
        if (g < e2) {
            const int r = rows[g];
            const int c = cols[g];
            const float v = vals[g];
            mybkt[k] = r >> BSH;
            myrec[k] = make_int2((c << BSH) | (r & (BROWS - 1)), __float_as_int(v));
            atomicAdd(&lh[mybkt[k]], 1);
        }
    }
    __syncthreads();

    // p2: block-local exclusive scan of lh -> lofs (2 elems/thread)
    const int i0 = 2 * t, i1 = 2 * t + 1;
    const int a0 = (i0 < NBKT) ? lh[i0] : 0;
    const int a1 = (i1 < NBKT) ? lh[i1] : 0;
    ssum[t] = a0 + a1;
    __syncthreads();
    for (int d = 1; d < BBLOCK; d <<= 1) {
        const int add = (t >= d) ? ssum[t - d] : 0;
        __syncthreads();
        ssum[t] += add;
        __syncthreads();
    }
    const int exc = ssum[t] - (a0 + a1);
    if (i0 < NBKT) lofs[i0] = exc;
    if (i1 < NBKT) lofs[i1] = exc + a0;
    __syncthreads();

    // cursors = lofs
    for (int k = t; k < NBKT; k += BBLOCK) lh[k] = lofs[k];
    __syncthreads();

    // p3: place records into LDS in bucket order
#pragma unroll
    for (int k = 0; k < EPT; ++k) {
        if (mybkt[k] >= 0) {
            const int pos = atomicAdd(&lh[mybkt[k]], 1);
            stage[pos] = myrec[k];
            sbkt[pos] = (unsigned short)mybkt[k];
        }
    }
    __syncthreads();

    // p4: reserve global runs (count = final cursor - lofs)
    for (int k = t; k < NBKT; k += BBLOCK) {
        const int c = lh[k] - lofs[k];
        gbase[k] = (c > 0) ? atomicAdd(&bktcnt[k], c) : 0;
    }
    __syncthreads();

    // p5: linear copy-out; consecutive threads -> consecutive global addrs
    for (int p = t; p < cnt_total; p += BBLOCK) {
        const int k = sbkt[p];
        const int g = gbase[k] + (p - lofs[k]);
        const int2 rec = stage[p];
        if (g < cap) {
            __builtin_nontemporal_store(
                *(const long long*)&rec,
                (long long*)(pack + (long long)k * cap + g));
        } else {
            const int o = atomicAdd(ovfcnt, 1);
            if (o < OVFCAP)
                ovfbuf[o] = make_int4((k << BSH) | (rec.x & (BROWS - 1)),
                                      rec.x >> BSH, rec.y, 0);
        }
    }
}

// ---------- gather: 2 blocks/bucket, 1-pass distribute, reg accum ----------
__global__ __launch_bounds__(GBLOCK, 8) void gather_kernel(
        const float* __restrict__ x,
        const float* __restrict__ weight,
        const int* __restrict__ idx_ptr,
        const int* __restrict__ bktcnt,
        const int2* __restrict__ pack,
        int* __restrict__ ovfcnt, int4* __restrict__ ovfbuf,
        float* __restrict__ out, int N, int cap) {
    __shared__ int2 slist[32 * LCAP];      // 11.3 KB (half-bucket: 32 rows)
    __shared__ int scur[32];
    const int b = blockIdx.x >> 1;         // bucket
    const int half = blockIdx.x & 1;       // rows half*32 .. half*32+31
    const int t = threadIdx.x;
    const int w = t >> 6;                  // wave 0..3 owns 8 local rows
    const int lane = t & 63;
    if (t < 32) scur[t] = 0;
    __syncthreads();
    const int cnt = min(bktcnt[b], cap);
    const long long* psrc = (const long long*)(pack + (long long)b * cap);
    for (int j = t; j < cnt; j += GBLOCK) {
        const long long raw = __builtin_nontemporal_load(psrc + j);
        const int2 rec = make_int2((int)(unsigned)raw, (int)(raw >> 32));
        const int rl = rec.x & (BROWS - 1);
        if ((rl >> 5) == half) {
            const int lrl = rl & 31;
            const int li = atomicAdd(&scur[lrl], 1);
            if (li < LCAP) {
                slist[lrl * LCAP + li] = rec;
            } else {
                const int o = atomicAdd(ovfcnt, 1);
                if (o < OVFCAP)
                    ovfbuf[o] = make_int4((b << BSH) | rl, rec.x >> BSH, rec.y, 0);
            }
        }
    }
    __syncthreads();
    const float ws = weight[idx_ptr[0]];
    float acc[8];
#pragma unroll
    for (int q = 0; q < 8; ++q) acc[q] = 0.f;
#pragma unroll
    for (int q = 0; q < 8; ++q) {
        const int lrl = w * 8 + q;
        const int n = min(scur[lrl], LCAP);
        const int2* lp = slist + lrl * LCAP;
        int j = 0;
        for (; j + 8 <= n; j += 8) {       // 8 independent x-row loads in flight
            const int2 r0 = lp[j],     r1 = lp[j + 1], r2 = lp[j + 2],
                       r3 = lp[j + 3], r4 = lp[j + 4], r5 = lp[j + 5],
                       r6 = lp[j + 6], r7 = lp[j + 7];
            const float x0 = x[(r0.x >> BSH) * FEAT_D + lane];
            const float x1 = x[(r1.x >> BSH) * FEAT_D + lane];
            const float x2 = x[(r2.x >> BSH) * FEAT_D + lane];
            const float x3 = x[(r3.x >> BSH) * FEAT_D + lane];
            const float x4 = x[(r4.x >> BSH) * FEAT_D + lane];
            const float x5 = x[(r5.x >> BSH) * FEAT_D + lane];
            const float x6 = x[(r6.x >> BSH) * FEAT_D + lane];
            const float x7 = x[(r7.x >> BSH) * FEAT_D + lane];
            acc[q] += __int_as_float(r0.y) * x0 + __int_as_float(r1.y) * x1 +
                      __int_as_float(r2.y) * x2 + __int_as_float(r3.y) * x3 +
                      __int_as_float(r4.y) * x4 + __int_as_float(r5.y) * x5 +
                      __int_as_float(r6.y) * x6 + __int_as_float(r7.y) * x7;
        }
        for (; j + 4 <= n; j += 4) {
            const int2 r0 = lp[j], r1 = lp[j + 1], r2 = lp[j + 2], r3 = lp[j + 3];
            const float x0 = x[(r0.x >> BSH) * FEAT_D + lane];
            const float x1 = x[(r1.x >> BSH) * FEAT_D + lane];
            const float x2 = x[(r2.x >> BSH) * FEAT_D + lane];
            const float x3 = x[(r3.x >> BSH) * FEAT_D + lane];
            acc[q] += __int_as_float(r0.y) * x0 + __int_as_float(r1.y) * x1 +
                      __int_as_float(r2.y) * x2 + __int_as_float(r3.y) * x3;
        }
        for (; j < n; ++j) {
            const int2 r0 = lp[j];
            acc[q] += __int_as_float(r0.y) * x[(r0.x >> BSH) * FEAT_D + lane];
        }
    }
    const int row0 = (b << BSH) + half * 32 + w * 8;
#pragma unroll
    for (int q = 0; q < 8; ++q) {
        const int row = row0 + q;
        if (row < N)
            __builtin_nontemporal_store(ws * acc[q],
                                        &out[(long long)row * FEAT_D + lane]);
    }
}

// ---------- fixup: apply overflow records (normally zero work) ----------
__global__ void fixup_kernel(const float* __restrict__ x,
                             const float* __restrict__ weight,
                             const int* __restrict__ idx_ptr,
                             const int* __restrict__ ovfcnt,
                             const int4* __restrict__ ovfbuf,
                             float* __restrict__ out) {
    const int n = min(*ovfcnt, OVFCAP);
    if (n == 0) return;
    const float ws = weight[idx_ptr[0]];
    const int gw = (int)((blockIdx.x * (long long)blockDim.x + threadIdx.x) >> 6);
    const int lane = threadIdx.x & 63;
    const int nw = (gridDim.x * blockDim.x) >> 6;
    for (int r = gw; r < n; r += nw) {
        const int4 rec = ovfbuf[r];
        atomicAdd(&out[(long long)rec.x * FEAT_D + lane],
                  ws * __int_as_float(rec.z) * x[(long long)rec.y * FEAT_D + lane]);
    }
}

// ---------- fallback (direct atomic scatter, always correct) ----------
__global__ void spmm_scatter_kernel(const float* __restrict__ x,
                                    const float* __restrict__ weight,
                                    const float* __restrict__ edge_vals,
                                    const int* __restrict__ edge_rows,
                                    const int* __restrict__ edge_cols,
                                    const int* __restrict__ idx_ptr,
                                    float* __restrict__ out,
                                    int E, long long work) {
    const int idx = idx_ptr[0];
    const float w = weight[idx];
    const long long rel_off = (long long)idx * E;
    long long t = (long long)blockIdx.x * blockDim.x + threadIdx.x;
    if (t >= work) return;
    const int e = (int)(t >> 4);
    const int q = (int)(t & 15);
    const int r = edge_rows[rel_off + e];
    const int c = edge_cols[rel_off + e];
    const float wv = w * edge_vals[rel_off + e];
    const float4 xv = *reinterpret_cast<const float4*>(x + (long long)c * FEAT_D + q * 4);
    float* op = out + (long long)r * FEAT_D + q * 4;
    atomicAdd(op + 0, wv * xv.x);
    atomicAdd(op + 1, wv * xv.y);
    atomicAdd(op + 2, wv * xv.z);
    atomicAdd(op + 3, wv * xv.w);
}

extern "C" void kernel_launch(void* const* d_in, const int* in_sizes, int n_in,
                              void* d_out, int out_size, void* d_ws, size_t ws_size,
                              hipStream_t stream) {
    const float* x         = (const float*)d_in[0];
    const float* weight    = (const float*)d_in[1];
    const float* edge_vals = (const float*)d_in[2];
    const int*   edge_rows = (const int*)d_in[3];
    const int*   edge_cols = (const int*)d_in[4];
    const int*   idx_ptr   = (const int*)d_in[5];
    float* out = (float*)d_out;

    const int R = in_sizes[1];
    const int E = in_sizes[2] / R;
    const int N = in_sizes[0] / FEAT_D;
    const int NBKT = (N + BROWS - 1) >> BSH;

    // ws layout: bktcnt[NBKT] | ovfcnt | pad | ovfbuf[OVFCAP]x16B | pack
    char* ws = (char*)d_ws;
    size_t o_bktcnt = 0;
    size_t o_ovfcnt = o_bktcnt + (size_t)NBKT * 4;
    size_t o_ovfbuf = ((o_ovfcnt + 4 + 15) / 16) * 16;
    size_t o_pack   = o_ovfbuf + (size_t)OVFCAP * 16;
    const size_t room = (ws_size > o_pack) ? (ws_size - o_pack) : 0;
    int cap = (int)(room / ((size_t)NBKT * 8));
    if (cap > 2048) cap = 2048;

    const long long meanload = (NBKT > 0) ? ((long long)E / NBKT) : 0;
    if (cap < 128 || cap < meanload + (meanload >> 3) + 32 || NBKT > MAXBKT) {
        hipMemsetAsync(d_out, 0, (size_t)out_size * sizeof(float), stream);
        const long long work = (long long)E * 16;
        const int block = 256;
        const long long grid = (work + block - 1) / block;
        spmm_scatter_kernel<<<dim3((unsigned)grid), dim3(block), 0, stream>>>(
            x, weight, edge_vals, edge_rows, edge_cols, idx_ptr, out, E, work);
        return;
    }

    int*  bktcnt = (int*)(ws + o_bktcnt);
    int*  ovfcnt = (int*)(ws + o_ovfcnt);
    int4* ovfbuf = (int4*)(ws + o_ovfbuf);
    int2* pack   = (int2*)(ws + o_pack);

    hipMemsetAsync(bktcnt, 0, (size_t)NBKT * 4 + 4, stream);

    const int bgrid = (E + EPB - 1) / EPB;
    build_kernel<<<bgrid, BBLOCK, 0, stream>>>(edge_vals, edge_rows,
                                               edge_cols, idx_ptr, bktcnt,
                                               pack, ovfcnt, ovfbuf,
                                               E, NBKT, cap);

    gather_kernel<<<NBKT * 2, GBLOCK, 0, stream>>>(x, weight, idx_ptr, bktcnt,
                                                   pack, ovfcnt, ovfbuf,
                                                   out, N, cap);

    fixup_kernel<<<64, 256, 0, stream>>>(x, weight, idx_ptr, ovfcnt, ovfbuf, out);
}

// Round 13
// 135.960 us; speedup vs baseline: 1.0301x; 1.0301x over previous
//
#include <hip/hip_runtime.h>

// SpMM out = w[idx] * segment_sum(vals[:,None] * x[cols], rows, N)
//
// Ladder: R1 atomics 680 -> R5 CSR 232 -> R8 bucket-bin+reg-gather 150.5 ->
// R10 138.8 -> R11 LDS-sorted build 135.6 -> R12 occupancy exp. regressed.
// Harness fill/restore ~60us fixed. Gather latency/L2-miss bound (~2.3TB/s
// random-line ceiling, measured R6/R9-R12). Build+memset ~35us controllable.
//
// R13: CHUNK-LOCAL CSR build - no global cursors, no memset, no write amp:
//  build block c sorts its 4096-edge chunk in LDS, writes records LINEARLY
//  to private region pack[c*EPB..] (coalesced 32KB stream) + ushort offset
//  table ofs[c][bucket]. Gather bucket b walks 196 (start,end) pairs from
//  the L2-resident table, distributes runs into per-row LDS lists, then
//  register-accumulates with unroll-8 (R11 geometry, 1 block/bucket).
//  3 dispatches total: build -> gather -> fixup.

#define FEAT_D 64
#define BROWS 64
#define BSH 6
#define MAXBKT 1024     // N <= 65536
#define LCAP 44         // per-row list cap; deg~Poisson(16), P(>44) ~ 1e-9
#define OVFCAP 16384
#define EPB 4096        // edges per build chunk
#define BBLOCK 512
#define EPT (EPB / BBLOCK)   // 8
#define GBLOCK 512      // 8 waves; wave w owns rows 8w..8w+7

// ---------- build: chunk-local LDS counting sort, linear copy-out ----------
__global__ __launch_bounds__(BBLOCK) void build_kernel(
        const float* __restrict__ edge_vals,
        const int* __restrict__ edge_rows,
        const int* __restrict__ edge_cols,
        const int* __restrict__ idx_ptr,
        int2* __restrict__ pack,
        unsigned short* __restrict__ ofs,
        int* __restrict__ ovfcnt,
        int E, int NBKT) {
    __shared__ int2 stage[EPB];            // 32 KB bucket-ordered records
    __shared__ int lh[MAXBKT];             // counts -> cursors
    __shared__ int lofs[MAXBKT];           // exclusive offsets
    __shared__ int ssum[BBLOCK];
    const long long off = (long long)idx_ptr[0] * E;
    const int* rows = edge_rows + off;
    const int* cols = edge_cols + off;
    const float* vals = edge_vals + off;
    const int t = threadIdx.x;
    const int c = blockIdx.x;
    const int s = c * EPB;
    const int e2 = min(s + EPB, E);
    const int cnt_total = e2 - s;

    for (int k = t; k < NBKT; k += BBLOCK) lh[k] = 0;
    if (c == 0 && t == 0) *ovfcnt = 0;     // replaces the memset dispatch
    __syncthreads();

    // p1: count; cache record + bucket in registers
    int2 myrec[EPT];
    int mybkt[EPT];
#pragma unroll
    for (int k = 0; k < EPT; ++k) {
        const int g = s + t + k * BBLOCK;
        mybkt[k] = -1;
        if (g < e2) {
            const int r = rows[g];
            const int col = cols[g];
            const float v = vals[g];
            mybkt[k] = r >> BSH;
            myrec[k] = make_int2((col << BSH) | (r & (BROWS - 1)), __float_as_int(v));
            atomicAdd(&lh[mybkt[k]], 1);
        }
    }
    __syncthreads();

    // p2: block-local exclusive scan of lh -> lofs (2 elems/thread)
    const int i0 = 2 * t, i1 = 2 * t + 1;
    const int a0 = (i0 < NBKT) ? lh[i0] : 0;
    const int a1 = (i1 < NBKT) ? lh[i1] : 0;
    ssum[t] = a0 + a1;
    __syncthreads();
    for (int d = 1; d < BBLOCK; d <<= 1) {
        const int add = (t >= d) ? ssum[t - d] : 0;
        __syncthreads();
        ssum[t] += add;
        __syncthreads();
    }
    const int exc = ssum[t] - (a0 + a1);
    if (i0 < NBKT) lofs[i0] = exc;
    if (i1 < NBKT) lofs[i1] = exc + a0;
    __syncthreads();

    // cursors = lofs
    for (int k = t; k < NBKT; k += BBLOCK) lh[k] = lofs[k];
    __syncthreads();

    // p3: place records into LDS in bucket order
#pragma unroll
    for (int k = 0; k < EPT; ++k) {
        if (mybkt[k] >= 0) {
            const int pos = atomicAdd(&lh[mybkt[k]], 1);
            stage[pos] = myrec[k];
        }
    }
    __syncthreads();

    // p4: offset table (ushort) for this chunk
    unsigned short* orow = ofs + (long long)c * (NBKT + 1);
    for (int k = t; k < NBKT; k += BBLOCK) orow[k] = (unsigned short)lofs[k];
    if (t == 0) orow[NBKT] = (unsigned short)cnt_total;

    // p5: LINEAR copy-out: consecutive threads -> consecutive addresses
    long long* dst = (long long*)(pack + (long long)c * EPB);
    const long long* src = (const long long*)stage;
    for (int p = t; p < cnt_total; p += BBLOCK)
        __builtin_nontemporal_store(src[p], dst + p);
}

// ---------- gather: block/bucket, chunk-run distribute, reg accum ----------
__global__ __launch_bounds__(GBLOCK) void gather_kernel(
        const float* __restrict__ x,
        const float* __restrict__ weight,
        const int* __restrict__ idx_ptr,
        const int2* __restrict__ pack,
        const unsigned short* __restrict__ ofs,
        int* __restrict__ ovfcnt, int4* __restrict__ ovfbuf,
        float* __restrict__ out, int N, int NBKT, int nchunks) {
    __shared__ int2 slist[BROWS * LCAP];   // 22.5 KB
    __shared__ int scur[BROWS];
    const int b = blockIdx.x;
    const int t = threadIdx.x;
    const int w = t >> 6;                  // wave 0..7 owns rows 8w..8w+7
    const int lane = t & 63;
    if (t < BROWS) scur[t] = 0;
    __syncthreads();
    // distribution: thread t walks chunk t's run for bucket b
    for (int c = t; c < nchunks; c += GBLOCK) {
        const unsigned short* op = ofs + (long long)c * (NBKT + 1) + b;
        const int rs = op[0];
        const int re = op[1];
        const long long* psrc = (const long long*)(pack + (long long)c * EPB);
        for (int p = rs; p < re; ++p) {
            const long long raw = __builtin_nontemporal_load(psrc + p);
            const int2 rec = make_int2((int)(unsigned)raw, (int)(raw >> 32));
            const int rl = rec.x & (BROWS - 1);
            const int li = atomicAdd(&scur[rl], 1);
            if (li < LCAP) {
                slist[rl * LCAP + li] = rec;
            } else {
                const int o = atomicAdd(ovfcnt, 1);
                if (o < OVFCAP)
                    ovfbuf[o] = make_int4((b << BSH) | rl, rec.x >> BSH, rec.y, 0);
            }
        }
    }
    __syncthreads();
    const float ws = weight[idx_ptr[0]];
    float acc[8];
#pragma unroll
    for (int q = 0; q < 8; ++q) acc[q] = 0.f;
#pragma unroll
    for (int q = 0; q < 8; ++q) {
        const int rl = w * 8 + q;
        const int n = min(scur[rl], LCAP);
        const int2* lp = slist + rl * LCAP;
        int j = 0;
        for (; j + 8 <= n; j += 8) {       // 8 independent x-row loads in flight
            const int2 r0 = lp[j],     r1 = lp[j + 1], r2 = lp[j + 2],
                       r3 = lp[j + 3], r4 = lp[j + 4], r5 = lp[j + 5],
                       r6 = lp[j + 6], r7 = lp[j + 7];
            const float x0 = x[(r0.x >> BSH) * FEAT_D + lane];
            const float x1 = x[(r1.x >> BSH) * FEAT_D + lane];
            const float x2 = x[(r2.x >> BSH) * FEAT_D + lane];
            const float x3 = x[(r3.x >> BSH) * FEAT_D + lane];
            const float x4 = x[(r4.x >> BSH) * FEAT_D + lane];
            const float x5 = x[(r5.x >> BSH) * FEAT_D + lane];
            const float x6 = x[(r6.x >> BSH) * FEAT_D + lane];
            const float x7 = x[(r7.x >> BSH) * FEAT_D + lane];
            acc[q] += __int_as_float(r0.y) * x0 + __int_as_float(r1.y) * x1 +
                      __int_as_float(r2.y) * x2 + __int_as_float(r3.y) * x3 +
                      __int_as_float(r4.y) * x4 + __int_as_float(r5.y) * x5 +
                      __int_as_float(r6.y) * x6 + __int_as_float(r7.y) * x7;
        }
        for (; j + 4 <= n; j += 4) {
            const int2 r0 = lp[j], r1 = lp[j + 1], r2 = lp[j + 2], r3 = lp[j + 3];
            const float x0 = x[(r0.x >> BSH) * FEAT_D + lane];
            const float x1 = x[(r1.x >> BSH) * FEAT_D + lane];
            const float x2 = x[(r2.x >> BSH) * FEAT_D + lane];
            const float x3 = x[(r3.x >> BSH) * FEAT_D + lane];
            acc[q] += __int_as_float(r0.y) * x0 + __int_as_float(r1.y) * x1 +
                      __int_as_float(r2.y) * x2 + __int_as_float(r3.y) * x3;
        }
        for (; j < n; ++j) {
            const int2 r0 = lp[j];
            acc[q] += __int_as_float(r0.y) * x[(r0.x >> BSH) * FEAT_D + lane];
        }
    }
    const int row0 = (b << BSH) + w * 8;
#pragma unroll
    for (int q = 0; q < 8; ++q) {
        const int row = row0 + q;
        if (row < N)
            __builtin_nontemporal_store(ws * acc[q],
                                        &out[(long long)row * FEAT_D + lane]);
    }
}

// ---------- fixup: apply overflow records (normally zero work) ----------
__global__ void fixup_kernel(const float* __restrict__ x,
                             const float* __restrict__ weight,
                             const int* __restrict__ idx_ptr,
                             const int* __restrict__ ovfcnt,
                             const int4* __restrict__ ovfbuf,
                             float* __restrict__ out) {
    const int n = min(*ovfcnt, OVFCAP);
    if (n == 0) return;
    const float ws = weight[idx_ptr[0]];
    const int gw = (int)((blockIdx.x * (long long)blockDim.x + threadIdx.x) >> 6);
    const int lane = threadIdx.x & 63;
    const int nw = (gridDim.x * blockDim.x) >> 6;
    for (int r = gw; r < n; r += nw) {
        const int4 rec = ovfbuf[r];
        atomicAdd(&out[(long long)rec.x * FEAT_D + lane],
                  ws * __int_as_float(rec.z) * x[(long long)rec.y * FEAT_D + lane]);
    }
}

// ---------- fallback (direct atomic scatter, always correct) ----------
__global__ void spmm_scatter_kernel(const float* __restrict__ x,
                                    const float* __restrict__ weight,
                                    const float* __restrict__ edge_vals,
                                    const int* __restrict__ edge_rows,
                                    const int* __restrict__ edge_cols,
                                    const int* __restrict__ idx_ptr,
                                    float* __restrict__ out,
                                    int E, long long work) {
    const int idx = idx_ptr[0];
    const float w = weight[idx];
    const long long rel_off = (long long)idx * E;
    long long t = (long long)blockIdx.x * blockDim.x + threadIdx.x;
    if (t >= work) return;
    const int e = (int)(t >> 4);
    const int q = (int)(t & 15);
    const int r = edge_rows[rel_off + e];
    const int c = edge_cols[rel_off + e];
    const float wv = w * edge_vals[rel_off + e];
    const float4 xv = *reinterpret_cast<const float4*>(x + (long long)c * FEAT_D + q * 4);
    float* op = out + (long long)r * FEAT_D + q * 4;
    atomicAdd(op + 0, wv * xv.x);
    atomicAdd(op + 1, wv * xv.y);
    atomicAdd(op + 2, wv * xv.z);
    atomicAdd(op + 3, wv * xv.w);
}

extern "C" void kernel_launch(void* const* d_in, const int* in_sizes, int n_in,
                              void* d_out, int out_size, void* d_ws, size_t ws_size,
                              hipStream_t stream) {
    const float* x         = (const float*)d_in[0];
    const float* weight    = (const float*)d_in[1];
    const float* edge_vals = (const float*)d_in[2];
    const int*   edge_rows = (const int*)d_in[3];
    const int*   edge_cols = (const int*)d_in[4];
    const int*   idx_ptr   = (const int*)d_in[5];
    float* out = (float*)d_out;

    const int R = in_sizes[1];
    const int E = in_sizes[2] / R;
    const int N = in_sizes[0] / FEAT_D;
    const int NBKT = (N + BROWS - 1) >> BSH;
    const int nchunks = (E + EPB - 1) / EPB;

    // ws layout: pack (8B) | ofs (2B) | ovfcnt | pad16 | ovfbuf
    char* ws = (char*)d_ws;
    size_t o_pack   = 0;
    size_t o_ofs    = o_pack + (size_t)nchunks * EPB * 8;
    size_t o_ovfcnt = o_ofs + (((size_t)nchunks * (NBKT + 1) * 2 + 7) & ~(size_t)7);
    size_t o_ovfbuf = ((o_ovfcnt + 4 + 15) / 16) * 16;
    size_t needed   = o_ovfbuf + (size_t)OVFCAP * 16;

    // EPB must fit ushort offsets; NBKT bounded by LDS tables
    if (ws_size < needed || NBKT > MAXBKT || N > MAXBKT * BROWS) {
        hipMemsetAsync(d_out, 0, (size_t)out_size * sizeof(float), stream);
        const long long work = (long long)E * 16;
        const int block = 256;
        const long long grid = (work + block - 1) / block;
        spmm_scatter_kernel<<<dim3((unsigned)grid), dim3(block), 0, stream>>>(
            x, weight, edge_vals, edge_rows, edge_cols, idx_ptr, out, E, work);
        return;
    }

    int2*           pack   = (int2*)(ws + o_pack);
    unsigned short* ofs    = (unsigned short*)(ws + o_ofs);
    int*            ovfcnt = (int*)(ws + o_ovfcnt);
    int4*           ovfbuf = (int4*)(ws + o_ovfbuf);

    build_kernel<<<nchunks, BBLOCK, 0, stream>>>(edge_vals, edge_rows,
                                                 edge_cols, idx_ptr,
                                                 pack, ofs, ovfcnt, E, NBKT);

    gather_kernel<<<NBKT, GBLOCK, 0, stream>>>(x, weight, idx_ptr, pack, ofs,
                                               ovfcnt, ovfbuf, out, N, NBKT,
                                               nchunks);

    fixup_kernel<<<64, 256, 0, stream>>>(x, weight, idx_ptr, ovfcnt, ovfbuf, out);
}